// Round 2
// baseline (142.263 us; speedup 1.0000x reference)
//
#include <hip/hip_runtime.h>

#define IMG_H 896
#define IMG_W 1344
#define NPIX (IMG_H * IMG_W)   // 1,204,224 = 301,056 * 4
#define PPT 4                  // pixels per thread
#define TPB 128                // threads per block
// grid = NPIX / (PPT*TPB) = 2352 exactly

// Fused per-pixel MLP 6->32->32->3 with relu, 4 pixels/thread.
// Weights stream through SGPRs (uniform s_load); each weight row now feeds
// 4 independent FMA chains, amortizing SMEM latency 4x vs 1 pixel/thread.
__global__ __launch_bounds__(TPB, 3) void mlp_pixel_kernel(
    const float* __restrict__ x,
    const float* __restrict__ w1, const float* __restrict__ b1,
    const float* __restrict__ w2, const float* __restrict__ b2,
    const float* __restrict__ w3, const float* __restrict__ b3,
    float* __restrict__ out)
{
    int t = blockIdx.x * TPB + threadIdx.x;      // thread id, 4 consecutive pixels
    if (t >= NPIX / PPT) return;

    // ---- load 4 pixels x 6 channels = 24 floats as 6 x float4 ----
    const float4* xp = reinterpret_cast<const float4*>(x + (size_t)t * (PPT * 6));
    float xi[PPT * 6];
#pragma unroll
    for (int k = 0; k < 6; ++k) {
        float4 f = xp[k];
        xi[k * 4 + 0] = f.x;
        xi[k * 4 + 1] = f.y;
        xi[k * 4 + 2] = f.z;
        xi[k * 4 + 3] = f.w;
    }
    // xi flat index = p*6 + j  (p = pixel 0..3, j = channel 0..5)

    // ---- layer-2 accumulators, init with bias ----
    float h2[PPT][32];
#pragma unroll
    for (int d = 0; d < 32; ++d) {
        float b = b2[d];
#pragma unroll
        for (int p = 0; p < PPT; ++p) h2[p][d] = b;
    }

    // ---- interleaved layer1+layer2: per hidden channel c, compute
    //      h1[c] for 4 pixels, relu, fold into all 32 h2 accumulators ----
#pragma unroll
    for (int c = 0; c < 32; ++c) {
        float h1c[PPT];
        float bc = b1[c];
#pragma unroll
        for (int p = 0; p < PPT; ++p) h1c[p] = bc;
#pragma unroll
        for (int j = 0; j < 6; ++j) {
            float w = w1[j * 32 + c];
#pragma unroll
            for (int p = 0; p < PPT; ++p)
                h1c[p] = fmaf(xi[p * 6 + j], w, h1c[p]);
        }
#pragma unroll
        for (int p = 0; p < PPT; ++p) h1c[p] = fmaxf(h1c[p], 0.0f);

#pragma unroll
        for (int d = 0; d < 32; ++d) {
            float w = w2[c * 32 + d];
#pragma unroll
            for (int p = 0; p < PPT; ++p)
                h2[p][d] = fmaf(h1c[p], w, h2[p][d]);
        }
    }

    // ---- layer 3: 32 -> 3 ----
    float o[PPT][3];
#pragma unroll
    for (int d = 0; d < 3; ++d) {
        float b = b3[d];
#pragma unroll
        for (int p = 0; p < PPT; ++p) o[p][d] = b;
    }
#pragma unroll
    for (int c = 0; c < 32; ++c) {
#pragma unroll
        for (int d = 0; d < 3; ++d) {
            float w = w3[c * 3 + d];
#pragma unroll
            for (int p = 0; p < PPT; ++p) {
                float h = fmaxf(h2[p][c], 0.0f);
                o[p][d] = fmaf(h, w, o[p][d]);
            }
        }
    }
    // note: relu(h2) recomputed per d (3x) — fmax is cheap; alternatively
    // apply in place first. Compiler CSEs the fmax across d anyway.

#pragma unroll
    for (int p = 0; p < PPT; ++p) {
#pragma unroll
        for (int d = 0; d < 3; ++d) o[p][d] = fmaxf(o[p][d], 0.0f);
    }

    // ---- store 4 pixels x 3 = 12 floats as 3 x float4 ----
    float4* op = reinterpret_cast<float4*>(out + (size_t)t * (PPT * 3));
    float4 s0 = {o[0][0], o[0][1], o[0][2], o[1][0]};
    float4 s1 = {o[1][1], o[1][2], o[2][0], o[2][1]};
    float4 s2 = {o[2][2], o[3][0], o[3][1], o[3][2]};
    op[0] = s0;
    op[1] = s1;
    op[2] = s2;
}

extern "C" void kernel_launch(void* const* d_in, const int* in_sizes, int n_in,
                              void* d_out, int out_size, void* d_ws, size_t ws_size,
                              hipStream_t stream) {
    const float* x  = (const float*)d_in[0];
    const float* w1 = (const float*)d_in[1];
    const float* b1 = (const float*)d_in[2];
    const float* w2 = (const float*)d_in[3];
    const float* b2 = (const float*)d_in[4];
    const float* w3 = (const float*)d_in[5];
    const float* b3 = (const float*)d_in[6];
    float* out = (float*)d_out;

    int grid = NPIX / (PPT * TPB);  // 2352 exactly
    mlp_pixel_kernel<<<grid, TPB, 0, stream>>>(x, w1, b1, w2, b2, w3, b3, out);
}